// Round 22
// baseline (481.430 us; speedup 1.0000x reference)
//
#include <hip/hip_runtime.h>

#define NBLK(n, b) (((n) + (b) - 1) / (b))

// fp32 feature stride: 96 floats = 384 B = 24 * float4
#define FS 96
#define FS4 24
// fp16 message table H: SINGLE table, 192B-aligned rows (12 x half8) -> gather
// touches exactly 3 cache lines/edge (R21-verified). gemm4 grid.y=3 symmetric
// (NT=2 tiles = 32 cols/block): each y-writer owns exactly ONE 64B line of the
// fp16 row (y0 line0, y1 line1, y2 line2) — cross-XCD false sharing impossible.
// Gather: one wave per node, 4 groups x 16 lanes, uniform csr index loads
// (R11/R18-verified). NO fused stats (R17/R19: global-atomic serialization).
// fill_k: XCD-partitioned (R18-verified). MFMA layouts [m89]: A lane=(row=l&15,
// k=(l>>4)*8+i), B lane=(col=l&15, same k), C/D col=l&15 row=(l>>4)*4+reg.
// W fp16 in LDS in B-fragment order (R16: one ds_read_b128 per fragment).

typedef _Float16 half8_t __attribute__((ext_vector_type(8)));
typedef float float8_t __attribute__((ext_vector_type(8)));
typedef float f32x4_t __attribute__((ext_vector_type(4)));

// ---------------- CSR build ----------------

__global__ void count_k(const int* __restrict__ dst, int* __restrict__ cnt, int e) {
  int i = blockIdx.x * blockDim.x + threadIdx.x;
  if (i < e) atomicAdd(&cnt[dst[i]], 1);
}

// scan1 also emits isq[i] = rsqrt(cnt[i]+1) (fused, saves a dispatch)
__global__ __launch_bounds__(256) void scan1_k(const int* __restrict__ cnt,
                                               int* __restrict__ rowptr,
                                               int* __restrict__ partials,
                                               float* __restrict__ isq, int n) {
  __shared__ int ls[256];
  const int t = threadIdx.x;
  const int base = blockIdx.x * 1024 + t * 4;
  int v0 = 0, v1 = 0, v2 = 0, v3 = 0;
  if (base + 3 < n) {
    int4 q = *reinterpret_cast<const int4*>(cnt + base);
    v0 = q.x; v1 = q.y; v2 = q.z; v3 = q.w;
  } else {
    if (base < n) v0 = cnt[base];
    if (base + 1 < n) v1 = cnt[base + 1];
    if (base + 2 < n) v2 = cnt[base + 2];
  }
  if (base + 3 < n) {
    float4 iq;
    iq.x = rsqrtf((float)v0 + 1.0f);
    iq.y = rsqrtf((float)v1 + 1.0f);
    iq.z = rsqrtf((float)v2 + 1.0f);
    iq.w = rsqrtf((float)v3 + 1.0f);
    *reinterpret_cast<float4*>(isq + base) = iq;
  } else {
    if (base < n) isq[base] = rsqrtf((float)v0 + 1.0f);
    if (base + 1 < n) isq[base + 1] = rsqrtf((float)v1 + 1.0f);
    if (base + 2 < n) isq[base + 2] = rsqrtf((float)v2 + 1.0f);
  }
  int s = v0 + v1 + v2 + v3;
  ls[t] = s;
  __syncthreads();
  for (int off = 1; off < 256; off <<= 1) {
    int u = (t >= off) ? ls[t - off] : 0;
    __syncthreads();
    ls[t] += u;
    __syncthreads();
  }
  int p = ls[t] - s;  // block-local exclusive
  if (t == 255) partials[blockIdx.x] = ls[255];
  if (base < n) rowptr[base] = p;
  p += v0;
  if (base + 1 < n) rowptr[base + 1] = p;
  p += v1;
  if (base + 2 < n) rowptr[base + 2] = p;
  p += v2;
  if (base + 3 < n) rowptr[base + 3] = p;
}

__global__ __launch_bounds__(256) void scan2_k(const int* __restrict__ partials,
                                               int* __restrict__ offsets, int B) {
  __shared__ int ls[256];
  const int t = threadIdx.x;
  int v = (t < B) ? partials[t] : 0;
  ls[t] = v;
  __syncthreads();
  for (int off = 1; off < 256; off <<= 1) {
    int u = (t >= off) ? ls[t - off] : 0;
    __syncthreads();
    ls[t] += u;
    __syncthreads();
  }
  if (t < B) offsets[t] = ls[t] - v;
  if (t == B - 1) offsets[B] = ls[t];
}

__global__ __launch_bounds__(256) void scan3_k(int* __restrict__ rowptr,
                                               int* __restrict__ cursor,
                                               const int* __restrict__ offsets,
                                               int n, int B) {
  const int t = threadIdx.x;
  const int base = blockIdx.x * 1024 + t * 4;
  const int off = offsets[blockIdx.x];
  if (base + 3 < n) {
    int4 q = *reinterpret_cast<const int4*>(rowptr + base);
    q.x += off; q.y += off; q.z += off; q.w += off;
    *reinterpret_cast<int4*>(rowptr + base) = q;
    *reinterpret_cast<int4*>(cursor + base) = q;
  } else {
    for (int i = base; i < n; ++i) {
      int v = rowptr[i] + off;
      rowptr[i] = v;
      cursor[i] = v;
    }
  }
  if (base == 0 && blockIdx.x == 0) rowptr[n] = offsets[B];
}

// XCD-partitioned fill (R18-verified): partition p = bid%8 owns dst-range.
__global__ __launch_bounds__(256) void fill_part_k(
    const int* __restrict__ src, const int* __restrict__ dst,
    int* __restrict__ cursor, unsigned short* __restrict__ csr, int e, int n) {
  const int p = blockIdx.x & 7;
  const int q = blockIdx.x >> 3;
  const int nb = gridDim.x >> 3;
  const int ps = (n + 7) >> 3;
  const int lo = p * ps;
  const int hi = min(lo + ps, n);
  const int stride = nb * 256;
  for (int i = q * 256 + threadIdx.x; i < e; i += stride) {
    const int d = dst[i];
    if (d >= lo && d < hi) {
      const int pos = atomicAdd(&cursor[d], 1);
      csr[pos] = (unsigned short)src[i];
    }
  }
}

// ---------------- MFMA GEMM: 64 rows x 32 cols per block (4 waves) ----------
// grid.y=3: y owns tiles {2y, 2y+1} = cols [32y, 32y+32). Each y-writer owns
// exactly one 64B line of each fp16 H row (and one 128B pair of fp32 rows).
// W pre-converted fp16 in LDS, B-fragment order (R16).
// XF: 0=x, 1=relu(x), 2=relu(x)*sc+sh, 3=relu(x*sc+sh)   (fp32, pre-convert)
// EPI: 0 = conv (fp16 acc*isq -> single 192B-row table), 1 = fc (fp32 acc+bias)

template <int K, int KP, int M, int INS, int OUTS, int XF, int EPI>
__global__ __launch_bounds__(256, 2) void gemm4_k(
    const float* __restrict__ X, const float* __restrict__ W,
    const float* __restrict__ bias, const float* __restrict__ isq,
    const float* __restrict__ scale, const float* __restrict__ shift,
    void* __restrict__ OUT, int n) {
  constexpr int KG = KP / 8;
  __shared__ _Float16 Wh[2 * KG * 16 * 8];
  const int t = threadIdx.x;
  const int tbase = blockIdx.y * 2;
  for (int idx = t; idx < KP * 32; idx += 256) {
    const int k = idx >> 5, cl = idx & 31;
    const int c = (tbase << 4) + cl;
    const float v = (k < K && c < M) ? W[k * M + c] : 0.0f;
    const int tt = cl >> 4, cc = cl & 15;
    Wh[((tt * KG + (k >> 3)) * 16 + cc) * 8 + (k & 7)] = (_Float16)v;
  }
  __syncthreads();
  const int wid = t >> 6;
  const int lane = t & 63;
  const int lr = lane & 15;         // A-row / B-col / D-col index
  const int hk = lane >> 4;         // k-subgroup (0..3), k offset = hk*8
  const int r0 = blockIdx.x * 64 + wid * 16;
  const int arow = min(r0 + lr, n - 1);
  const float* __restrict__ xp = X + (size_t)arow * INS;
  const half8_t* __restrict__ Whv = reinterpret_cast<const half8_t*>(Wh);
  f32x4_t acc[2];
#pragma unroll
  for (int tt = 0; tt < 2; ++tt) acc[tt] = (f32x4_t){0.0f, 0.0f, 0.0f, 0.0f};
  for (int ks = 0; ks < KP; ks += 32) {
    const int kb = ks + hk * 8;
    float a[8];
    {
      float4 v0 = *reinterpret_cast<const float4*>(xp + kb);
      float4 v1 = *reinterpret_cast<const float4*>(xp + kb + 4);
      a[0] = v0.x; a[1] = v0.y; a[2] = v0.z; a[3] = v0.w;
      a[4] = v1.x; a[5] = v1.y; a[6] = v1.z; a[7] = v1.w;
    }
    if constexpr (XF == 1) {
#pragma unroll
      for (int i = 0; i < 8; ++i) a[i] = fmaxf(a[i], 0.0f);
    } else if constexpr (XF == 2 || XF == 3) {
      float4 s0 = *reinterpret_cast<const float4*>(scale + kb);
      float4 s1 = *reinterpret_cast<const float4*>(scale + kb + 4);
      float4 h0 = *reinterpret_cast<const float4*>(shift + kb);
      float4 h1 = *reinterpret_cast<const float4*>(shift + kb + 4);
      const float sc[8] = {s0.x, s0.y, s0.z, s0.w, s1.x, s1.y, s1.z, s1.w};
      const float shf[8] = {h0.x, h0.y, h0.z, h0.w, h1.x, h1.y, h1.z, h1.w};
#pragma unroll
      for (int i = 0; i < 8; ++i) {
        if constexpr (XF == 2) a[i] = fmaxf(a[i], 0.0f) * sc[i] + shf[i];
        else a[i] = fmaxf(a[i] * sc[i] + shf[i], 0.0f);
      }
    }
    half8_t af;
#pragma unroll
    for (int i = 0; i < 8; ++i) af[i] = (_Float16)a[i];
    const int kg = kb >> 3;
#pragma unroll
    for (int tt = 0; tt < 2; ++tt) {
      half8_t bf = Whv[(tt * KG + kg) * 16 + lr];
      acc[tt] = __builtin_amdgcn_mfma_f32_16x16x32_f16(af, bf, acc[tt], 0, 0, 0);
    }
  }
  // epilogue: D col = (tbase+tt)*16 + lr, rows rg..rg+3
  const int rg = r0 + (hk << 2);
  if constexpr (EPI == 0) {
    float siq[4];
#pragma unroll
    for (int j = 0; j < 4; ++j) siq[j] = (rg + j < n) ? isq[rg + j] : 0.0f;
    _Float16* Hh = (_Float16*)OUT;
#pragma unroll
    for (int tt = 0; tt < 2; ++tt) {
      const int c = (tbase + tt) * 16 + lr;
#pragma unroll
      for (int j = 0; j < 4; ++j) {
        const int row = rg + j;
        if (row < n)
          Hh[(size_t)row * 96 + c] = (_Float16)(acc[tt][j] * siq[j]);
      }
    }
  } else {
    float* O = (float*)OUT;
#pragma unroll
    for (int tt = 0; tt < 2; ++tt) {
      const int c = (tbase + tt) * 16 + lr;
      const float bv = (c < M) ? bias[c] : 0.0f;
#pragma unroll
      for (int j = 0; j < 4; ++j) {
        const int row = rg + j;
        if (row < n) O[(size_t)row * OUTS + c] = acc[tt][j] + bv;
      }
    }
  }
}

// ---------------- thread-per-row gemm (small fc layers) ----------------

template <int K, int KP, int M, int MH, int INS, int OUTS, int XF, int EPI>
__global__ __launch_bounds__(256, 2) void gemm2_k(
    const float* __restrict__ X, const float* __restrict__ W,
    const float* __restrict__ bias, const float* __restrict__ isq,
    const float* __restrict__ scale, const float* __restrict__ shift,
    void* __restrict__ OUT, int n) {
  __shared__ float Ws[KP * MH];
  __shared__ float Sc[(XF >= 2) ? KP : 1];
  __shared__ float Sh[(XF >= 2) ? KP : 1];
  const int ms = blockIdx.y;
  for (int idx = threadIdx.x; idx < KP * MH; idx += 256) {
    int k = idx / MH;
    int m = idx - k * MH;
    int col = ms * MH + m;
    Ws[idx] = (k < K && col < M) ? W[k * M + col] : 0.0f;
  }
  if constexpr (XF >= 2) {
    for (int k = threadIdx.x; k < KP; k += 256) {
      Sc[k] = (k < K) ? scale[k] : 0.0f;
      Sh[k] = (k < K) ? shift[k] : 0.0f;
    }
  }
  __syncthreads();
  const int row = blockIdx.x * 256 + threadIdx.x;
  const bool valid = row < n;
  const float* xp = X + (size_t)(valid ? row : 0) * INS;
  float acc[MH];
#pragma unroll
  for (int m = 0; m < MH; ++m) acc[m] = 0.0f;
  for (int k0 = 0; k0 < KP; k0 += 4) {
    float4 tt = *reinterpret_cast<const float4*>(xp + k0);
    float xv[4] = {tt.x, tt.y, tt.z, tt.w};
#pragma unroll
    for (int j = 0; j < 4; ++j) {
      float xval = xv[j];
      if constexpr (XF == 1) xval = fmaxf(xval, 0.0f);
      if constexpr (XF == 2) xval = fmaxf(xval, 0.0f) * Sc[k0 + j] + Sh[k0 + j];
      if constexpr (XF == 3) xval = fmaxf(xval * Sc[k0 + j] + Sh[k0 + j], 0.0f);
      const float* wrow = &Ws[(k0 + j) * MH];
#pragma unroll
      for (int m = 0; m < MH; ++m) acc[m] += xval * wrow[m];
    }
  }
  if (!valid) return;
  float* O = (float*)OUT;
  const size_t base = (size_t)row * OUTS + ms * MH;
#pragma unroll
  for (int m = 0; m < MH; ++m) O[base + m] = acc[m] + bias[ms * MH + m];
}

// ---------------- CSR gather-reduce: one WAVE per destination node ----------
// Single 192B-row table: lanes s<12 load 12 contiguous half8 = 3 lines/edge.
// 4 groups x 16 lanes; group g handles ordinals beg+g+4k; uniform csr loads;
// shfl_xor(16,32) reduce. (R11/R18/R21-verified.)

__global__ __launch_bounds__(256, 6) void gather_k(
    const _Float16* __restrict__ H, const int* __restrict__ rowptr,
    const unsigned short* __restrict__ csr, const float* __restrict__ isq,
    const float* __restrict__ bias, float* __restrict__ A, int n) {
  const int wid = threadIdx.x >> 6;
  const int lane = threadIdx.x & 63;
  const int d = blockIdx.x * 4 + wid;
  if (d >= n) return;
  const int g = lane >> 4;   // group 0..3
  const int s = lane & 15;   // slot; active when s < 12
  const int beg = rowptr[d];
  const int end = rowptr[d + 1];
  const half8_t* __restrict__ Hp = reinterpret_cast<const half8_t*>(H);
  const half8_t* __restrict__ lanebase = Hp + ((s < 12) ? s : 0);
  float8_t acc = {0, 0, 0, 0, 0, 0, 0, 0};
  float8_t acc2 = {0, 0, 0, 0, 0, 0, 0, 0};
  if (lane < 12)  // self row (already * isq[src] from gemm)
    acc += __builtin_convertvector(lanebase[(size_t)d * 12], float8_t);
  int r = beg + g;
  for (; r + 4 < end; r += 8) {
    const int v0 = (int)csr[r];
    const int v1 = (int)csr[r + 4];
    if (s < 12) {
      acc += __builtin_convertvector(lanebase[(size_t)v0 * 12], float8_t);
      acc2 += __builtin_convertvector(lanebase[(size_t)v1 * 12], float8_t);
    }
  }
  for (; r < end; r += 4) {
    const int v = (int)csr[r];
    if (s < 12) acc += __builtin_convertvector(lanebase[(size_t)v * 12], float8_t);
  }
  acc += acc2;
#pragma unroll
  for (int i = 0; i < 8; ++i) acc[i] += __shfl_xor(acc[i], 16);
#pragma unroll
  for (int i = 0; i < 8; ++i) acc[i] += __shfl_xor(acc[i], 32);
  if (lane < 12) {
    const float sc = isq[d];
    const int c = lane * 8;
    float o[8];
#pragma unroll
    for (int i = 0; i < 8; ++i)
      o[i] = acc[i] * sc + ((c + i < 90) ? bias[c + i] : 0.0f);
    float4* Ap = reinterpret_cast<float4*>(A + (size_t)d * FS + c);
    Ap[0] = make_float4(o[0], o[1], o[2], o[3]);
    Ap[1] = make_float4(o[4], o[5], o[6], o[7]);
  }
}

// ---------------- bn stats over an FS-strided fp32 buffer ----------------

template <int M, bool RELU>
__global__ __launch_bounds__(256) void bn_stats4_k(const float* __restrict__ X,
                                                   float* __restrict__ gsum,
                                                   float* __restrict__ gsq, int n) {
  __shared__ float ssum[FS];
  __shared__ float ssq[FS];
  for (int i = threadIdx.x; i < FS; i += 256) { ssum[i] = 0.0f; ssq[i] = 0.0f; }
  __syncthreads();
  const int t = threadIdx.x;
  const int cq = t % FS4;
  const int rl = t / FS4;
  constexpr int ROWS = 256 / FS4;  // 10
  const float4* __restrict__ Xp = reinterpret_cast<const float4*>(X);
  if (rl < ROWS) {
    float s0 = 0, s1 = 0, s2 = 0, s3 = 0, q0 = 0, q1 = 0, q2 = 0, q3 = 0;
    for (int r = blockIdx.x * ROWS + rl; r < n; r += gridDim.x * ROWS) {
      float4 v = Xp[(size_t)r * FS4 + cq];
      if (RELU) {
        v.x = fmaxf(v.x, 0.0f); v.y = fmaxf(v.y, 0.0f);
        v.z = fmaxf(v.z, 0.0f); v.w = fmaxf(v.w, 0.0f);
      }
      s0 += v.x; q0 += v.x * v.x;
      s1 += v.y; q1 += v.y * v.y;
      s2 += v.z; q2 += v.z * v.z;
      s3 += v.w; q3 += v.w * v.w;
    }
    const int c = cq * 4;
    if (c + 0 < M) { atomicAdd(&ssum[c + 0], s0); atomicAdd(&ssq[c + 0], q0); }
    if (c + 1 < M) { atomicAdd(&ssum[c + 1], s1); atomicAdd(&ssq[c + 1], q1); }
    if (c + 2 < M) { atomicAdd(&ssum[c + 2], s2); atomicAdd(&ssq[c + 2], q2); }
    if (c + 3 < M) { atomicAdd(&ssum[c + 3], s3); atomicAdd(&ssq[c + 3], q3); }
  }
  __syncthreads();
  for (int i = threadIdx.x; i < M; i += 256) {
    atomicAdd(&gsum[i], ssum[i]);
    atomicAdd(&gsq[i], ssq[i]);
  }
}

// ---------------- batchnorm finalize ----------------

template <int M>
__global__ void bn_final_k(const float* __restrict__ gsum, const float* __restrict__ gsq,
                           const float* __restrict__ g, const float* __restrict__ b,
                           float* __restrict__ scale, float* __restrict__ shift, float invn) {
  int c = threadIdx.x;
  if (c >= FS) return;
  if (c >= M) { scale[c] = 0.0f; shift[c] = 0.0f; return; }
  float mu = gsum[c] * invn;
  float var = gsq[c] * invn - mu * mu;
  float r = rsqrtf(var + 1e-5f);
  float sc = g[c] * r;
  scale[c] = sc;
  shift[c] = b[c] - mu * sc;
}

// ---------------- launch ----------------

extern "C" void kernel_launch(void* const* d_in, const int* in_sizes, int n_in,
                              void* d_out, int out_size, void* d_ws, size_t ws_size,
                              hipStream_t stream) {
  const float* x = (const float*)d_in[0];
  const int* ei = (const int*)d_in[1];
  const float* conv1_w = (const float*)d_in[2];
  const float* conv1_b = (const float*)d_in[3];
  const float* convs_w = (const float*)d_in[4];
  const float* convs_b = (const float*)d_in[5];
  const float* bn1_g = (const float*)d_in[6];
  const float* bn1_b = (const float*)d_in[7];
  const float* fc1_w = (const float*)d_in[8];
  const float* fc1_b = (const float*)d_in[9];
  const float* bn2_g = (const float*)d_in[10];
  const float* bn2_b = (const float*)d_in[11];
  const float* fc2_w = (const float*)d_in[12];
  const float* fc2_b = (const float*)d_in[13];
  const float* bn3_g = (const float*)d_in[14];
  const float* bn3_b = (const float*)d_in[15];
  const float* fc3_w = (const float*)d_in[16];
  const float* fc3_b = (const float*)d_in[17];

  const int N = in_sizes[0] / 128;
  const int E = in_sizes[1] / 2;
  const int* src = ei;
  const int* dst = ei + E;
  const int B = NBLK(N, 1024);

  // workspace layout (all chunks >=256B-aligned)
  float* ws = (float*)d_ws;
  float* isq = ws;                              // N
  int* rowptr = (int*)(ws + 50048);             // N+1
  int* cursor = rowptr + 50048;                 // N
  int* cnt = cursor + 50048;                    // N
  unsigned short* csr16 = (unsigned short*)(cnt + 50048);  // E ushorts
  int* partials = (int*)(csr16 + 800000);       // 64
  int* offsets = partials + 64;                 // 64+2
  float* stats = (float*)(offsets + 128);       // 5 * 192 (sum @ +0, sq @ +96)
  float* scale = stats + 5 * 192;               // 96
  float* shift = scale + 96;                    // 96
  float* bufH = shift + 96;                     // N*FS floats (fp16 192B-row table)
  float* bufA = bufH + (size_t)N * FS;          // N*FS floats
  _Float16* bufHh = (_Float16*)bufH;

  float* gs0 = stats + 0 * 192; float* gq0 = gs0 + 96;
  float* gs1 = stats + 1 * 192; float* gq1 = gs1 + 96;
  float* gs2 = stats + 2 * 192; float* gq2 = gs2 + 96;
  float* gs3 = stats + 3 * 192; float* gq3 = gs3 + 96;
  float* gs4 = stats + 4 * 192; float* gq4 = gs4 + 96;

  // ---- CSR build + norm ----
  hipMemsetAsync(cnt, 0, 50048 * sizeof(int), stream);
  hipMemsetAsync(stats, 0, 5 * 192 * sizeof(float), stream);
  count_k<<<NBLK(E, 256), 256, 0, stream>>>(dst, cnt, E);
  scan1_k<<<B, 256, 0, stream>>>(cnt, rowptr, partials, isq, N);
  scan2_k<<<1, 256, 0, stream>>>(partials, offsets, B);
  scan3_k<<<B, 256, 0, stream>>>(rowptr, cursor, offsets, N, B);
  fill_part_k<<<1024, 256, 0, stream>>>(src, dst, cursor, csr16, E, N);

  const int grows = NBLK(N, 256);
  const int gmf = NBLK(N, 64);
  const int ggath = NBLK(N, 4);
  const float invn = 1.0f / (float)N;

  // ---- conv1: x[N,128] -> H, gather -> A ----
  gemm4_k<128, 128, 90, 128, FS, 0, 0><<<dim3(gmf, 3), 256, 0, stream>>>(
      x, conv1_w, nullptr, isq, nullptr, nullptr, bufHh, N);
  gather_k<<<ggath, 256, 0, stream>>>(bufHh, rowptr, csr16, isq, conv1_b, bufA, N);

  // ---- conv2 ----
  gemm4_k<90, 96, 90, FS, FS, 1, 0><<<dim3(gmf, 3), 256, 0, stream>>>(
      bufA, convs_w, nullptr, isq, nullptr, nullptr, bufHh, N);
  gather_k<<<ggath, 256, 0, stream>>>(bufHh, rowptr, csr16, isq, convs_b, bufA, N);
  bn_stats4_k<90, true><<<512, 256, 0, stream>>>(bufA, gs0, gq0, N);
  bn_final_k<90><<<1, 128, 0, stream>>>(gs0, gq0, bn1_g, bn1_b, scale, shift, invn);

  // ---- conv3 ----
  gemm4_k<90, 96, 90, FS, FS, 2, 0><<<dim3(gmf, 3), 256, 0, stream>>>(
      bufA, convs_w + 90 * 90, nullptr, isq, scale, shift, bufHh, N);
  gather_k<<<ggath, 256, 0, stream>>>(bufHh, rowptr, csr16, isq, convs_b + 90, bufA, N);
  bn_stats4_k<90, true><<<512, 256, 0, stream>>>(bufA, gs1, gq1, N);
  bn_final_k<90><<<1, 128, 0, stream>>>(gs1, gq1, bn1_g, bn1_b, scale, shift, invn);

  // ---- conv4 ----
  gemm4_k<90, 96, 90, FS, FS, 2, 0><<<dim3(gmf, 3), 256, 0, stream>>>(
      bufA, convs_w + 2 * 90 * 90, nullptr, isq, scale, shift, bufHh, N);
  gather_k<<<ggath, 256, 0, stream>>>(bufHh, rowptr, csr16, isq, convs_b + 2 * 90, bufA, N);
  bn_stats4_k<90, true><<<512, 256, 0, stream>>>(bufA, gs2, gq2, N);
  bn_final_k<90><<<1, 128, 0, stream>>>(gs2, gq2, bn1_g, bn1_b, scale, shift, invn);

  // ---- fc1: relu+bn1 -> 80 (fp32 out into bufH) ----
  gemm4_k<90, 96, 80, FS, FS, 2, 1><<<dim3(gmf, 3), 256, 0, stream>>>(
      bufA, fc1_w, fc1_b, nullptr, scale, shift, bufH, N);
  bn_stats4_k<80, false><<<512, 256, 0, stream>>>(bufH, gs3, gq3, N);
  bn_final_k<80><<<1, 128, 0, stream>>>(gs3, gq3, bn2_g, bn2_b, scale, shift, invn);

  // ---- fc2: bn2+relu -> 50 ----
  gemm2_k<80, 80, 50, 25, FS, FS, 3, 1><<<dim3(grows, 2), 256, 0, stream>>>(
      bufH, fc2_w, fc2_b, nullptr, scale, shift, bufA, N);
  bn_stats4_k<50, false><<<512, 256, 0, stream>>>(bufA, gs4, gq4, N);
  bn_final_k<50><<<1, 128, 0, stream>>>(gs4, gq4, bn3_g, bn3_b, scale, shift, invn);

  // ---- fc3: bn3+relu -> 1 ----
  gemm2_k<50, 52, 1, 1, FS, 1, 3, 1><<<dim3(grows, 1), 256, 0, stream>>>(
      bufA, fc3_w, fc3_b, nullptr, scale, shift, (float*)d_out, N);
}

// Round 23
// 458.376 us; speedup vs baseline: 1.0503x; 1.0503x over previous
//
#include <hip/hip_runtime.h>

#define NBLK(n, b) (((n) + (b) - 1) / (b))

// fp32 feature stride: 96 floats = 384 B = 24 * float4
#define FS 96
#define FS4 24
// fp16 message table H: SINGLE table, 192B-aligned rows (12 x half8) -> gather
// touches exactly 3 cache lines/edge (R21-verified). gemm4 grid.y=2 ASYMMETRIC
// 4/2 tiles (R21-verified best): y0 writes bytes 0-127 (lines 0-1), y1 writes
// bytes 128-191 (line 2) — line-disjoint writers, no cross-XCD false sharing.
// R22 lesson: grid.y=3 (NT=2) regressed — W-staging amortization loss > occ win.
// Gather: one wave per node, 4 groups x 16 lanes, uniform csr index loads
// (R11/R18-verified). NO fused stats (R17/R19: global-atomic serialization).
// fill_k: XCD-partitioned (R18-verified). MFMA layouts [m89]: A lane=(row=l&15,
// k=(l>>4)*8+i), B lane=(col=l&15, same k), C/D col=l&15 row=(l>>4)*4+reg.
// W fp16 in LDS in B-fragment order (R16: one ds_read_b128 per fragment).

typedef _Float16 half8_t __attribute__((ext_vector_type(8)));
typedef float float8_t __attribute__((ext_vector_type(8)));
typedef float f32x4_t __attribute__((ext_vector_type(4)));

// ---------------- CSR build ----------------

__global__ void count_k(const int* __restrict__ dst, int* __restrict__ cnt, int e) {
  int i = blockIdx.x * blockDim.x + threadIdx.x;
  if (i < e) atomicAdd(&cnt[dst[i]], 1);
}

// scan1 also emits isq[i] = rsqrt(cnt[i]+1) (fused, saves a dispatch)
__global__ __launch_bounds__(256) void scan1_k(const int* __restrict__ cnt,
                                               int* __restrict__ rowptr,
                                               int* __restrict__ partials,
                                               float* __restrict__ isq, int n) {
  __shared__ int ls[256];
  const int t = threadIdx.x;
  const int base = blockIdx.x * 1024 + t * 4;
  int v0 = 0, v1 = 0, v2 = 0, v3 = 0;
  if (base + 3 < n) {
    int4 q = *reinterpret_cast<const int4*>(cnt + base);
    v0 = q.x; v1 = q.y; v2 = q.z; v3 = q.w;
  } else {
    if (base < n) v0 = cnt[base];
    if (base + 1 < n) v1 = cnt[base + 1];
    if (base + 2 < n) v2 = cnt[base + 2];
  }
  if (base + 3 < n) {
    float4 iq;
    iq.x = rsqrtf((float)v0 + 1.0f);
    iq.y = rsqrtf((float)v1 + 1.0f);
    iq.z = rsqrtf((float)v2 + 1.0f);
    iq.w = rsqrtf((float)v3 + 1.0f);
    *reinterpret_cast<float4*>(isq + base) = iq;
  } else {
    if (base < n) isq[base] = rsqrtf((float)v0 + 1.0f);
    if (base + 1 < n) isq[base + 1] = rsqrtf((float)v1 + 1.0f);
    if (base + 2 < n) isq[base + 2] = rsqrtf((float)v2 + 1.0f);
  }
  int s = v0 + v1 + v2 + v3;
  ls[t] = s;
  __syncthreads();
  for (int off = 1; off < 256; off <<= 1) {
    int u = (t >= off) ? ls[t - off] : 0;
    __syncthreads();
    ls[t] += u;
    __syncthreads();
  }
  int p = ls[t] - s;  // block-local exclusive
  if (t == 255) partials[blockIdx.x] = ls[255];
  if (base < n) rowptr[base] = p;
  p += v0;
  if (base + 1 < n) rowptr[base + 1] = p;
  p += v1;
  if (base + 2 < n) rowptr[base + 2] = p;
  p += v2;
  if (base + 3 < n) rowptr[base + 3] = p;
}

__global__ __launch_bounds__(256) void scan2_k(const int* __restrict__ partials,
                                               int* __restrict__ offsets, int B) {
  __shared__ int ls[256];
  const int t = threadIdx.x;
  int v = (t < B) ? partials[t] : 0;
  ls[t] = v;
  __syncthreads();
  for (int off = 1; off < 256; off <<= 1) {
    int u = (t >= off) ? ls[t - off] : 0;
    __syncthreads();
    ls[t] += u;
    __syncthreads();
  }
  if (t < B) offsets[t] = ls[t] - v;
  if (t == B - 1) offsets[B] = ls[t];
}

__global__ __launch_bounds__(256) void scan3_k(int* __restrict__ rowptr,
                                               int* __restrict__ cursor,
                                               const int* __restrict__ offsets,
                                               int n, int B) {
  const int t = threadIdx.x;
  const int base = blockIdx.x * 1024 + t * 4;
  const int off = offsets[blockIdx.x];
  if (base + 3 < n) {
    int4 q = *reinterpret_cast<const int4*>(rowptr + base);
    q.x += off; q.y += off; q.z += off; q.w += off;
    *reinterpret_cast<int4*>(rowptr + base) = q;
    *reinterpret_cast<int4*>(cursor + base) = q;
  } else {
    for (int i = base; i < n; ++i) {
      int v = rowptr[i] + off;
      rowptr[i] = v;
      cursor[i] = v;
    }
  }
  if (base == 0 && blockIdx.x == 0) rowptr[n] = offsets[B];
}

// XCD-partitioned fill (R18-verified): partition p = bid%8 owns dst-range.
__global__ __launch_bounds__(256) void fill_part_k(
    const int* __restrict__ src, const int* __restrict__ dst,
    int* __restrict__ cursor, unsigned short* __restrict__ csr, int e, int n) {
  const int p = blockIdx.x & 7;
  const int q = blockIdx.x >> 3;
  const int nb = gridDim.x >> 3;
  const int ps = (n + 7) >> 3;
  const int lo = p * ps;
  const int hi = min(lo + ps, n);
  const int stride = nb * 256;
  for (int i = q * 256 + threadIdx.x; i < e; i += stride) {
    const int d = dst[i];
    if (d >= lo && d < hi) {
      const int pos = atomicAdd(&cursor[d], 1);
      csr[pos] = (unsigned short)src[i];
    }
  }
}

// ---------------- MFMA GEMM: 64 rows x (4|2)*16 cols per block (4 waves) ----
// grid.y=2 asymmetric: y0 -> tiles 0..3 (cols 0-63), y1 -> tiles 4..5 (64-95).
// Line-disjoint H writes (fp16 row: y0 bytes 0-127, y1 bytes 128-191).
// W pre-converted fp16 in LDS, B-fragment order; ntiles uniform per block.
// XF: 0=x, 1=relu(x), 2=relu(x)*sc+sh, 3=relu(x*sc+sh)   (fp32, pre-convert)
// EPI: 0 = conv (fp16 acc*isq -> single 192B-row table), 1 = fc (fp32 acc+bias)

template <int K, int KP, int M, int INS, int OUTS, int XF, int EPI>
__global__ __launch_bounds__(256, 2) void gemm4_k(
    const float* __restrict__ X, const float* __restrict__ W,
    const float* __restrict__ bias, const float* __restrict__ isq,
    const float* __restrict__ scale, const float* __restrict__ shift,
    void* __restrict__ OUT, int n) {
  constexpr int KG = KP / 8;
  __shared__ _Float16 Wh[4 * KG * 16 * 8];
  const int t = threadIdx.x;
  const int ybl = blockIdx.y;
  const int ntiles = ybl ? 2 : 4;
  const int tbase = ybl ? 4 : 0;
  const int nt16 = ntiles << 4;
  const int sh = ybl ? 5 : 6;  // log2(nt16)
  for (int idx = t; idx < KP * nt16; idx += 256) {
    const int k = idx >> sh, cl = idx & (nt16 - 1);
    const int c = (tbase << 4) + cl;
    const float v = (k < K && c < M) ? W[k * M + c] : 0.0f;
    const int tt = cl >> 4, cc = cl & 15;
    Wh[((tt * KG + (k >> 3)) * 16 + cc) * 8 + (k & 7)] = (_Float16)v;
  }
  __syncthreads();
  const int wid = t >> 6;
  const int lane = t & 63;
  const int lr = lane & 15;         // A-row / B-col / D-col index
  const int hk = lane >> 4;         // k-subgroup (0..3), k offset = hk*8
  const int r0 = blockIdx.x * 64 + wid * 16;
  const int arow = min(r0 + lr, n - 1);
  const float* __restrict__ xp = X + (size_t)arow * INS;
  const half8_t* __restrict__ Whv = reinterpret_cast<const half8_t*>(Wh);
  f32x4_t acc[4];
#pragma unroll
  for (int tt = 0; tt < 4; ++tt) acc[tt] = (f32x4_t){0.0f, 0.0f, 0.0f, 0.0f};
  for (int ks = 0; ks < KP; ks += 32) {
    const int kb = ks + hk * 8;
    float a[8];
    {
      float4 v0 = *reinterpret_cast<const float4*>(xp + kb);
      float4 v1 = *reinterpret_cast<const float4*>(xp + kb + 4);
      a[0] = v0.x; a[1] = v0.y; a[2] = v0.z; a[3] = v0.w;
      a[4] = v1.x; a[5] = v1.y; a[6] = v1.z; a[7] = v1.w;
    }
    if constexpr (XF == 1) {
#pragma unroll
      for (int i = 0; i < 8; ++i) a[i] = fmaxf(a[i], 0.0f);
    } else if constexpr (XF == 2 || XF == 3) {
      float4 s0 = *reinterpret_cast<const float4*>(scale + kb);
      float4 s1 = *reinterpret_cast<const float4*>(scale + kb + 4);
      float4 h0 = *reinterpret_cast<const float4*>(shift + kb);
      float4 h1 = *reinterpret_cast<const float4*>(shift + kb + 4);
      const float sc[8] = {s0.x, s0.y, s0.z, s0.w, s1.x, s1.y, s1.z, s1.w};
      const float shf[8] = {h0.x, h0.y, h0.z, h0.w, h1.x, h1.y, h1.z, h1.w};
#pragma unroll
      for (int i = 0; i < 8; ++i) {
        if constexpr (XF == 2) a[i] = fmaxf(a[i], 0.0f) * sc[i] + shf[i];
        else a[i] = fmaxf(a[i] * sc[i] + shf[i], 0.0f);
      }
    }
    half8_t af;
#pragma unroll
    for (int i = 0; i < 8; ++i) af[i] = (_Float16)a[i];
    const int kg = kb >> 3;
#pragma unroll
    for (int tt = 0; tt < 4; ++tt) {
      if (tt < ntiles) {
        half8_t bf = Whv[(tt * KG + kg) * 16 + lr];
        acc[tt] = __builtin_amdgcn_mfma_f32_16x16x32_f16(af, bf, acc[tt], 0, 0, 0);
      }
    }
  }
  // epilogue: D col = (tbase+tt)*16 + lr, rows rg..rg+3
  const int rg = r0 + (hk << 2);
  if constexpr (EPI == 0) {
    float siq[4];
#pragma unroll
    for (int j = 0; j < 4; ++j) siq[j] = (rg + j < n) ? isq[rg + j] : 0.0f;
    _Float16* Hh = (_Float16*)OUT;
#pragma unroll
    for (int tt = 0; tt < 4; ++tt) {
      if (tt < ntiles) {
        const int c = (tbase + tt) * 16 + lr;
#pragma unroll
        for (int j = 0; j < 4; ++j) {
          const int row = rg + j;
          if (row < n)
            Hh[(size_t)row * 96 + c] = (_Float16)(acc[tt][j] * siq[j]);
        }
      }
    }
  } else {
    float* O = (float*)OUT;
#pragma unroll
    for (int tt = 0; tt < 4; ++tt) {
      if (tt < ntiles) {
        const int c = (tbase + tt) * 16 + lr;
        const float bv = (c < M) ? bias[c] : 0.0f;
#pragma unroll
        for (int j = 0; j < 4; ++j) {
          const int row = rg + j;
          if (row < n) O[(size_t)row * OUTS + c] = acc[tt][j] + bv;
        }
      }
    }
  }
}

// ---------------- thread-per-row gemm (small fc layers) ----------------

template <int K, int KP, int M, int MH, int INS, int OUTS, int XF, int EPI>
__global__ __launch_bounds__(256, 2) void gemm2_k(
    const float* __restrict__ X, const float* __restrict__ W,
    const float* __restrict__ bias, const float* __restrict__ isq,
    const float* __restrict__ scale, const float* __restrict__ shift,
    void* __restrict__ OUT, int n) {
  __shared__ float Ws[KP * MH];
  __shared__ float Sc[(XF >= 2) ? KP : 1];
  __shared__ float Sh[(XF >= 2) ? KP : 1];
  const int ms = blockIdx.y;
  for (int idx = threadIdx.x; idx < KP * MH; idx += 256) {
    int k = idx / MH;
    int m = idx - k * MH;
    int col = ms * MH + m;
    Ws[idx] = (k < K && col < M) ? W[k * M + col] : 0.0f;
  }
  if constexpr (XF >= 2) {
    for (int k = threadIdx.x; k < KP; k += 256) {
      Sc[k] = (k < K) ? scale[k] : 0.0f;
      Sh[k] = (k < K) ? shift[k] : 0.0f;
    }
  }
  __syncthreads();
  const int row = blockIdx.x * 256 + threadIdx.x;
  const bool valid = row < n;
  const float* xp = X + (size_t)(valid ? row : 0) * INS;
  float acc[MH];
#pragma unroll
  for (int m = 0; m < MH; ++m) acc[m] = 0.0f;
  for (int k0 = 0; k0 < KP; k0 += 4) {
    float4 tt = *reinterpret_cast<const float4*>(xp + k0);
    float xv[4] = {tt.x, tt.y, tt.z, tt.w};
#pragma unroll
    for (int j = 0; j < 4; ++j) {
      float xval = xv[j];
      if constexpr (XF == 1) xval = fmaxf(xval, 0.0f);
      if constexpr (XF == 2) xval = fmaxf(xval, 0.0f) * Sc[k0 + j] + Sh[k0 + j];
      if constexpr (XF == 3) xval = fmaxf(xval * Sc[k0 + j] + Sh[k0 + j], 0.0f);
      const float* wrow = &Ws[(k0 + j) * MH];
#pragma unroll
      for (int m = 0; m < MH; ++m) acc[m] += xval * wrow[m];
    }
  }
  if (!valid) return;
  float* O = (float*)OUT;
  const size_t base = (size_t)row * OUTS + ms * MH;
#pragma unroll
  for (int m = 0; m < MH; ++m) O[base + m] = acc[m] + bias[ms * MH + m];
}

// ---------------- CSR gather-reduce: one WAVE per destination node ----------
// Single 192B-row table: lanes s<12 load 12 contiguous half8 = 3 lines/edge.
// 4 groups x 16 lanes; group g handles ordinals beg+g+4k; uniform csr loads;
// shfl_xor(16,32) reduce. (R11/R18/R21-verified.)

__global__ __launch_bounds__(256, 6) void gather_k(
    const _Float16* __restrict__ H, const int* __restrict__ rowptr,
    const unsigned short* __restrict__ csr, const float* __restrict__ isq,
    const float* __restrict__ bias, float* __restrict__ A, int n) {
  const int wid = threadIdx.x >> 6;
  const int lane = threadIdx.x & 63;
  const int d = blockIdx.x * 4 + wid;
  if (d >= n) return;
  const int g = lane >> 4;   // group 0..3
  const int s = lane & 15;   // slot; active when s < 12
  const int beg = rowptr[d];
  const int end = rowptr[d + 1];
  const half8_t* __restrict__ Hp = reinterpret_cast<const half8_t*>(H);
  const half8_t* __restrict__ lanebase = Hp + ((s < 12) ? s : 0);
  float8_t acc = {0, 0, 0, 0, 0, 0, 0, 0};
  float8_t acc2 = {0, 0, 0, 0, 0, 0, 0, 0};
  if (lane < 12)  // self row (already * isq[src] from gemm)
    acc += __builtin_convertvector(lanebase[(size_t)d * 12], float8_t);
  int r = beg + g;
  for (; r + 4 < end; r += 8) {
    const int v0 = (int)csr[r];
    const int v1 = (int)csr[r + 4];
    if (s < 12) {
      acc += __builtin_convertvector(lanebase[(size_t)v0 * 12], float8_t);
      acc2 += __builtin_convertvector(lanebase[(size_t)v1 * 12], float8_t);
    }
  }
  for (; r < end; r += 4) {
    const int v = (int)csr[r];
    if (s < 12) acc += __builtin_convertvector(lanebase[(size_t)v * 12], float8_t);
  }
  acc += acc2;
#pragma unroll
  for (int i = 0; i < 8; ++i) acc[i] += __shfl_xor(acc[i], 16);
#pragma unroll
  for (int i = 0; i < 8; ++i) acc[i] += __shfl_xor(acc[i], 32);
  if (lane < 12) {
    const float sc = isq[d];
    const int c = lane * 8;
    float o[8];
#pragma unroll
    for (int i = 0; i < 8; ++i)
      o[i] = acc[i] * sc + ((c + i < 90) ? bias[c + i] : 0.0f);
    float4* Ap = reinterpret_cast<float4*>(A + (size_t)d * FS + c);
    Ap[0] = make_float4(o[0], o[1], o[2], o[3]);
    Ap[1] = make_float4(o[4], o[5], o[6], o[7]);
  }
}

// ---------------- bn stats over an FS-strided fp32 buffer ----------------

template <int M, bool RELU>
__global__ __launch_bounds__(256) void bn_stats4_k(const float* __restrict__ X,
                                                   float* __restrict__ gsum,
                                                   float* __restrict__ gsq, int n) {
  __shared__ float ssum[FS];
  __shared__ float ssq[FS];
  for (int i = threadIdx.x; i < FS; i += 256) { ssum[i] = 0.0f; ssq[i] = 0.0f; }
  __syncthreads();
  const int t = threadIdx.x;
  const int cq = t % FS4;
  const int rl = t / FS4;
  constexpr int ROWS = 256 / FS4;  // 10
  const float4* __restrict__ Xp = reinterpret_cast<const float4*>(X);
  if (rl < ROWS) {
    float s0 = 0, s1 = 0, s2 = 0, s3 = 0, q0 = 0, q1 = 0, q2 = 0, q3 = 0;
    for (int r = blockIdx.x * ROWS + rl; r < n; r += gridDim.x * ROWS) {
      float4 v = Xp[(size_t)r * FS4 + cq];
      if (RELU) {
        v.x = fmaxf(v.x, 0.0f); v.y = fmaxf(v.y, 0.0f);
        v.z = fmaxf(v.z, 0.0f); v.w = fmaxf(v.w, 0.0f);
      }
      s0 += v.x; q0 += v.x * v.x;
      s1 += v.y; q1 += v.y * v.y;
      s2 += v.z; q2 += v.z * v.z;
      s3 += v.w; q3 += v.w * v.w;
    }
    const int c = cq * 4;
    if (c + 0 < M) { atomicAdd(&ssum[c + 0], s0); atomicAdd(&ssq[c + 0], q0); }
    if (c + 1 < M) { atomicAdd(&ssum[c + 1], s1); atomicAdd(&ssq[c + 1], q1); }
    if (c + 2 < M) { atomicAdd(&ssum[c + 2], s2); atomicAdd(&ssq[c + 2], q2); }
    if (c + 3 < M) { atomicAdd(&ssum[c + 3], s3); atomicAdd(&ssq[c + 3], q3); }
  }
  __syncthreads();
  for (int i = threadIdx.x; i < M; i += 256) {
    atomicAdd(&gsum[i], ssum[i]);
    atomicAdd(&gsq[i], ssq[i]);
  }
}

// ---------------- batchnorm finalize ----------------

template <int M>
__global__ void bn_final_k(const float* __restrict__ gsum, const float* __restrict__ gsq,
                           const float* __restrict__ g, const float* __restrict__ b,
                           float* __restrict__ scale, float* __restrict__ shift, float invn) {
  int c = threadIdx.x;
  if (c >= FS) return;
  if (c >= M) { scale[c] = 0.0f; shift[c] = 0.0f; return; }
  float mu = gsum[c] * invn;
  float var = gsq[c] * invn - mu * mu;
  float r = rsqrtf(var + 1e-5f);
  float sc = g[c] * r;
  scale[c] = sc;
  shift[c] = b[c] - mu * sc;
}

// ---------------- launch ----------------

extern "C" void kernel_launch(void* const* d_in, const int* in_sizes, int n_in,
                              void* d_out, int out_size, void* d_ws, size_t ws_size,
                              hipStream_t stream) {
  const float* x = (const float*)d_in[0];
  const int* ei = (const int*)d_in[1];
  const float* conv1_w = (const float*)d_in[2];
  const float* conv1_b = (const float*)d_in[3];
  const float* convs_w = (const float*)d_in[4];
  const float* convs_b = (const float*)d_in[5];
  const float* bn1_g = (const float*)d_in[6];
  const float* bn1_b = (const float*)d_in[7];
  const float* fc1_w = (const float*)d_in[8];
  const float* fc1_b = (const float*)d_in[9];
  const float* bn2_g = (const float*)d_in[10];
  const float* bn2_b = (const float*)d_in[11];
  const float* fc2_w = (const float*)d_in[12];
  const float* fc2_b = (const float*)d_in[13];
  const float* bn3_g = (const float*)d_in[14];
  const float* bn3_b = (const float*)d_in[15];
  const float* fc3_w = (const float*)d_in[16];
  const float* fc3_b = (const float*)d_in[17];

  const int N = in_sizes[0] / 128;
  const int E = in_sizes[1] / 2;
  const int* src = ei;
  const int* dst = ei + E;
  const int B = NBLK(N, 1024);

  // workspace layout (all chunks >=256B-aligned)
  float* ws = (float*)d_ws;
  float* isq = ws;                              // N
  int* rowptr = (int*)(ws + 50048);             // N+1
  int* cursor = rowptr + 50048;                 // N
  int* cnt = cursor + 50048;                    // N
  unsigned short* csr16 = (unsigned short*)(cnt + 50048);  // E ushorts
  int* partials = (int*)(csr16 + 800000);       // 64
  int* offsets = partials + 64;                 // 64+2
  float* stats = (float*)(offsets + 128);       // 5 * 192 (sum @ +0, sq @ +96)
  float* scale = stats + 5 * 192;               // 96
  float* shift = scale + 96;                    // 96
  float* bufH = shift + 96;                     // N*FS floats (fp16 192B-row table)
  float* bufA = bufH + (size_t)N * FS;          // N*FS floats
  _Float16* bufHh = (_Float16*)bufH;

  float* gs0 = stats + 0 * 192; float* gq0 = gs0 + 96;
  float* gs1 = stats + 1 * 192; float* gq1 = gs1 + 96;
  float* gs2 = stats + 2 * 192; float* gq2 = gs2 + 96;
  float* gs3 = stats + 3 * 192; float* gq3 = gs3 + 96;
  float* gs4 = stats + 4 * 192; float* gq4 = gs4 + 96;

  // ---- CSR build + norm ----
  hipMemsetAsync(cnt, 0, 50048 * sizeof(int), stream);
  hipMemsetAsync(stats, 0, 5 * 192 * sizeof(float), stream);
  count_k<<<NBLK(E, 256), 256, 0, stream>>>(dst, cnt, E);
  scan1_k<<<B, 256, 0, stream>>>(cnt, rowptr, partials, isq, N);
  scan2_k<<<1, 256, 0, stream>>>(partials, offsets, B);
  scan3_k<<<B, 256, 0, stream>>>(rowptr, cursor, offsets, N, B);
  fill_part_k<<<1024, 256, 0, stream>>>(src, dst, cursor, csr16, E, N);

  const int grows = NBLK(N, 256);
  const int gmf = NBLK(N, 64);
  const int ggath = NBLK(N, 4);
  const float invn = 1.0f / (float)N;

  // ---- conv1: x[N,128] -> H, gather -> A ----
  gemm4_k<128, 128, 90, 128, FS, 0, 0><<<dim3(gmf, 2), 256, 0, stream>>>(
      x, conv1_w, nullptr, isq, nullptr, nullptr, bufHh, N);
  gather_k<<<ggath, 256, 0, stream>>>(bufHh, rowptr, csr16, isq, conv1_b, bufA, N);

  // ---- conv2 ----
  gemm4_k<90, 96, 90, FS, FS, 1, 0><<<dim3(gmf, 2), 256, 0, stream>>>(
      bufA, convs_w, nullptr, isq, nullptr, nullptr, bufHh, N);
  gather_k<<<ggath, 256, 0, stream>>>(bufHh, rowptr, csr16, isq, convs_b, bufA, N);
  bn_stats4_k<90, true><<<512, 256, 0, stream>>>(bufA, gs0, gq0, N);
  bn_final_k<90><<<1, 128, 0, stream>>>(gs0, gq0, bn1_g, bn1_b, scale, shift, invn);

  // ---- conv3 ----
  gemm4_k<90, 96, 90, FS, FS, 2, 0><<<dim3(gmf, 2), 256, 0, stream>>>(
      bufA, convs_w + 90 * 90, nullptr, isq, scale, shift, bufHh, N);
  gather_k<<<ggath, 256, 0, stream>>>(bufHh, rowptr, csr16, isq, convs_b + 90, bufA, N);
  bn_stats4_k<90, true><<<512, 256, 0, stream>>>(bufA, gs1, gq1, N);
  bn_final_k<90><<<1, 128, 0, stream>>>(gs1, gq1, bn1_g, bn1_b, scale, shift, invn);

  // ---- conv4 ----
  gemm4_k<90, 96, 90, FS, FS, 2, 0><<<dim3(gmf, 2), 256, 0, stream>>>(
      bufA, convs_w + 2 * 90 * 90, nullptr, isq, scale, shift, bufHh, N);
  gather_k<<<ggath, 256, 0, stream>>>(bufHh, rowptr, csr16, isq, convs_b + 2 * 90, bufA, N);
  bn_stats4_k<90, true><<<512, 256, 0, stream>>>(bufA, gs2, gq2, N);
  bn_final_k<90><<<1, 128, 0, stream>>>(gs2, gq2, bn1_g, bn1_b, scale, shift, invn);

  // ---- fc1: relu+bn1 -> 80 (fp32 out into bufH) ----
  gemm4_k<90, 96, 80, FS, FS, 2, 1><<<dim3(gmf, 2), 256, 0, stream>>>(
      bufA, fc1_w, fc1_b, nullptr, scale, shift, bufH, N);
  bn_stats4_k<80, false><<<512, 256, 0, stream>>>(bufH, gs3, gq3, N);
  bn_final_k<80><<<1, 128, 0, stream>>>(gs3, gq3, bn2_g, bn2_b, scale, shift, invn);

  // ---- fc2: bn2+relu -> 50 ----
  gemm2_k<80, 80, 50, 25, FS, FS, 3, 1><<<dim3(grows, 2), 256, 0, stream>>>(
      bufH, fc2_w, fc2_b, nullptr, scale, shift, bufA, N);
  bn_stats4_k<50, false><<<512, 256, 0, stream>>>(bufA, gs4, gq4, N);
  bn_final_k<50><<<1, 128, 0, stream>>>(gs4, gq4, bn3_g, bn3_b, scale, shift, invn);

  // ---- fc3: bn3+relu -> 1 ----
  gemm2_k<50, 52, 1, 1, FS, 1, 3, 1><<<dim3(grows, 1), 256, 0, stream>>>(
      bufA, fc3_w, fc3_b, nullptr, scale, shift, (float*)d_out, N);
}